// Round 4
// baseline (1417.482 us; speedup 1.0000x reference)
//
#include <hip/hip_runtime.h>
#include <hip/hip_bf16.h>
#include <stdint.h>

#define B_ 16
#define N_ 64
#define S_ 4096
#define C_ 384
#define H_ 6
#define DH_ 64
#define SCALE_ 0.125f
#define TAU_ 2e-4f
#define LISTCAP 262144

typedef __attribute__((ext_vector_type(8))) short bf16x8;
typedef __attribute__((ext_vector_type(4))) float f32x4;

static __device__ __forceinline__ unsigned short f2bf(float x) {
    union { float f; unsigned u; } v; v.f = x;
    unsigned r = v.u + 0x7FFFu + ((v.u >> 16) & 1u);
    return (unsigned short)(r >> 16);
}
static __device__ __forceinline__ float bf2f(unsigned short b) {
    union { unsigned u; float f; } v; v.u = ((unsigned)b) << 16; return v.f;
}

// async global->LDS, 16B/lane; LDS dest = wave-uniform base + lane*16
static __device__ __forceinline__ void gl_lds16(const void* g, void* l) {
    __builtin_amdgcn_global_load_lds(
        (const __attribute__((address_space(1))) unsigned int*)g,
        (__attribute__((address_space(3))) unsigned int*)l, 16, 0, 0);
}

// ---------------------------------------------------------------------------
// K0: prep — key -> khi/klo (bf16 hi + bf16 residual)
// ---------------------------------------------------------------------------
__global__ __launch_bounds__(256) void prep_kernel(const float* __restrict__ key,
                                                   unsigned short* __restrict__ khi,
                                                   unsigned short* __restrict__ klo) {
    size_t gid = (size_t)blockIdx.x * 256 + threadIdx.x;
    size_t base = gid * 8;
    float4 x0 = *(const float4*)(key + base);
    float4 x1 = *(const float4*)(key + base + 4);
    float xs[8] = { x0.x, x0.y, x0.z, x0.w, x1.x, x1.y, x1.z, x1.w };
    unsigned short hi[8], lo[8];
#pragma unroll
    for (int i = 0; i < 8; ++i) {
        hi[i] = f2bf(xs[i]);
        lo[i] = f2bf(xs[i] - bf2f(hi[i]));
    }
    *(bf16x8*)(khi + base) = *(bf16x8*)hi;
    *(bf16x8*)(klo + base) = *(bf16x8*)lo;
}

// ---------------------------------------------------------------------------
// K1: fused q-proj + qk (fp32 exact) + bf16 hi/lo split of qk
// ---------------------------------------------------------------------------
__global__ __launch_bounds__(384) void qk_fused_kernel(const float* __restrict__ query,
                                                       const float* __restrict__ Wq,
                                                       const float* __restrict__ Wk,
                                                       float* __restrict__ qk,
                                                       unsigned short* __restrict__ qkhi,
                                                       unsigned short* __restrict__ qklo) {
    __shared__ float qstage[8][C_];
    __shared__ float qrow[8][C_];
    int ng = blockIdx.x, b = blockIdx.y;
    int t = threadIdx.x;
    int n0 = ng * 8;
#pragma unroll
    for (int i = 0; i < 8; ++i)
        qstage[i][t] = query[((size_t)(b * N_ + n0 + i)) * C_ + t];
    __syncthreads();
    {
        float a[8];
#pragma unroll
        for (int i = 0; i < 8; ++i) a[i] = 0.f;
        const float4* wq = (const float4*)(Wq + (size_t)t * C_);
        for (int c4 = 0; c4 < C_ / 4; ++c4) {
            float4 w = wq[c4];
#pragma unroll
            for (int i = 0; i < 8; ++i)
                a[i] += qstage[i][c4 * 4 + 0] * w.x + qstage[i][c4 * 4 + 1] * w.y
                      + qstage[i][c4 * 4 + 2] * w.z + qstage[i][c4 * 4 + 3] * w.w;
        }
#pragma unroll
        for (int i = 0; i < 8; ++i) qrow[i][t] = a[i] * SCALE_;
    }
    __syncthreads();
    for (int h = 0; h < H_; ++h) {
        float a[8];
#pragma unroll
        for (int i = 0; i < 8; ++i) a[i] = 0.f;
        const float* wk = Wk + (size_t)h * DH_ * C_ + t;
#pragma unroll 4
        for (int d = 0; d < DH_; ++d) {
            float w = wk[(size_t)d * C_];
#pragma unroll
            for (int i = 0; i < 8; ++i) a[i] += qrow[i][h * DH_ + d] * w;
        }
#pragma unroll
        for (int i = 0; i < 8; ++i) {
            size_t o = ((size_t)(b * H_ + h) * N_ + n0 + i) * C_ + t;
            float v = a[i];
            qk[o] = v;
            unsigned short hi = f2bf(v);
            qkhi[o] = hi;
            qklo[o] = f2bf(v - bf2f(hi));
        }
    }
}

// ---------------------------------------------------------------------------
// K2: logits via 3-pass bf16 MFMA + argmax. 64n x 256 tokens (round-2 shape),
// XOR-swizzled LDS quarters (conflict-free, verified round 3).
// NOTE: plain launch_bounds — round 3 showed (256,6) forces scratch spill.
// ---------------------------------------------------------------------------
__global__ __launch_bounds__(256) void attn_kernel(const unsigned short* __restrict__ qkhi,
                                                   const unsigned short* __restrict__ qklo,
                                                   const unsigned short* __restrict__ khi,
                                                   const unsigned short* __restrict__ klo,
                                                   unsigned int* __restrict__ idx,
                                                   unsigned int* __restrict__ flag_cnt,
                                                   unsigned int* __restrict__ flag_list) {
    __shared__ __align__(16) unsigned short sAhi[64 * 32];
    __shared__ __align__(16) unsigned short sAlo[64 * 32];
    __shared__ __align__(16) unsigned short sBhi[256 * 32];
    __shared__ __align__(16) unsigned short sBlo[256 * 32];
    int tid = threadIdx.x;
    int w = tid >> 6, l = tid & 63;
    int wm = w >> 1, wn = w & 1;
    int q4 = l >> 4, lm = l & 15;
    int s0 = blockIdx.x * 256;
    int h = blockIdx.y, b = blockIdx.z;
    size_t kbK = ((size_t)b * S_ + s0) * C_;
    size_t kbA = (size_t)(b * H_ + h) * N_ * C_;
    int trow16 = l >> 2;
    int tquart = ((l & 3) ^ ((l >> 3) & 3)) * 8;   // swizzled source quarter
    int sw = (q4 ^ ((lm >> 1) & 3)) * 8;           // swizzled read quarter

    f32x4 acc[2][8];
#pragma unroll
    for (int tm = 0; tm < 2; ++tm)
#pragma unroll
        for (int nt = 0; nt < 8; ++nt) acc[tm][nt] = (f32x4)0.f;

    for (int kc = 0; kc < C_; kc += 32) {
        __syncthreads();
#pragma unroll
        for (int i = 0; i < 10; ++i) {
            int gid = w * 10 + i;
            if (gid < 16) {
                gl_lds16(khi + kbK + (size_t)(gid * 16 + trow16) * C_ + kc + tquart,
                         (char*)sBhi + gid * 1024);
            } else if (gid < 32) {
                int g2 = gid - 16;
                gl_lds16(klo + kbK + (size_t)(g2 * 16 + trow16) * C_ + kc + tquart,
                         (char*)sBlo + g2 * 1024);
            } else if (gid < 36) {
                int g2 = gid - 32;
                gl_lds16(qkhi + kbA + (size_t)(g2 * 16 + trow16) * C_ + kc + tquart,
                         (char*)sAhi + g2 * 1024);
            } else {
                int g2 = gid - 36;
                gl_lds16(qklo + kbA + (size_t)(g2 * 16 + trow16) * C_ + kc + tquart,
                         (char*)sAlo + g2 * 1024);
            }
        }
        __syncthreads();
        bf16x8 ah[2], al[2];
#pragma unroll
        for (int tm = 0; tm < 2; ++tm) {
            int ar = (wm * 32 + tm * 16 + lm) * 32 + sw;
            ah[tm] = *(const bf16x8*)&sAhi[ar];
            al[tm] = *(const bf16x8*)&sAlo[ar];
        }
#pragma unroll
        for (int nt = 0; nt < 8; ++nt) {
            int nr = ((wn * 8 + nt) * 16 + lm) * 32 + sw;
            bf16x8 bh = *(const bf16x8*)&sBhi[nr];
            bf16x8 bl = *(const bf16x8*)&sBlo[nr];
#pragma unroll
            for (int tm = 0; tm < 2; ++tm) {
                acc[tm][nt] = __builtin_amdgcn_mfma_f32_16x16x32_bf16(ah[tm], bh, acc[tm][nt], 0, 0, 0);
                acc[tm][nt] = __builtin_amdgcn_mfma_f32_16x16x32_bf16(ah[tm], bl, acc[tm][nt], 0, 0, 0);
                acc[tm][nt] = __builtin_amdgcn_mfma_f32_16x16x32_bf16(al[tm], bh, acc[tm][nt], 0, 0, 0);
            }
        }
    }
    __syncthreads();

    float* rm1 = (float*)sBhi;            // [2][256]
    float* rm2 = rm1 + 512;
    int* ri1 = (int*)(rm2 + 512);
    int* ri2 = ri1 + 512;

#pragma unroll
    for (int nt = 0; nt < 8; ++nt) {
        float m1 = -3.4e38f, m2 = -3.4e38f; int i1 = 0, i2 = 0;
#pragma unroll
        for (int tm = 0; tm < 2; ++tm)
#pragma unroll
            for (int r = 0; r < 4; ++r) {
                float v = acc[tm][nt][r];
                int row = wm * 32 + tm * 16 + q4 * 4 + r;
                if (v > m1) { m2 = m1; i2 = i1; m1 = v; i1 = row; }
                else if (v > m2) { m2 = v; i2 = row; }
            }
#pragma unroll
        for (int off = 16; off < 64; off <<= 1) {
            float om1 = __shfl_xor(m1, off), om2 = __shfl_xor(m2, off);
            int oi1 = __shfl_xor(i1, off), oi2 = __shfl_xor(i2, off);
            bool take = (om1 > m1) || (om1 == m1 && oi1 < i1);
            float w1 = take ? om1 : m1; int wi1 = take ? oi1 : i1;
            float l1 = take ? m1 : om1; int li1 = take ? i1 : oi1;
            float s2 = m2; int si2 = i2;
            if (om2 > s2) { s2 = om2; si2 = oi2; }
            if (l1 > s2) { s2 = l1; si2 = li1; }
            m1 = w1; i1 = wi1; m2 = s2; i2 = si2;
        }
        if (q4 == 0) {
            int cw = (wn * 8 + nt) * 16 + lm;
            rm1[wm * 256 + cw] = m1; rm2[wm * 256 + cw] = m2;
            ri1[wm * 256 + cw] = i1; ri2[wm * 256 + cw] = i2;
        }
    }
    __syncthreads();
    float a1 = rm1[tid], a2 = rm2[tid];
    int ai1 = ri1[tid], ai2 = ri2[tid];
    float b1 = rm1[256 + tid], b2 = rm2[256 + tid];
    int bi1 = ri1[256 + tid], bi2 = ri2[256 + tid];
    float w1, s2; int wi1, wi2;
    if (b1 > a1) { w1 = b1; wi1 = bi1; s2 = a1; wi2 = ai1; if (b2 > s2) { s2 = b2; wi2 = bi2; } }
    else         { w1 = a1; wi1 = ai1; s2 = a2; wi2 = ai2; if (b1 > s2) { s2 = b1; wi2 = bi1; } }
    idx[(size_t)(b * H_ + h) * S_ + s0 + tid] = (unsigned)wi1;
    if (w1 - s2 < TAU_) {
        unsigned p = atomicAdd(flag_cnt, 1u);
        if (p < LISTCAP) {
            unsigned tok = (unsigned)((b * H_ + h) * S_ + s0 + tid);
            flag_list[p] = tok | ((unsigned)wi1 << 19) | ((unsigned)wi2 << 25);
        }
    }
}

// ---------------------------------------------------------------------------
// K3: fixup — exact fp32 recompute of two candidate rows for near-ties
// ---------------------------------------------------------------------------
__global__ __launch_bounds__(256) void fixup_kernel(const float* __restrict__ qk,
                                                    const float* __restrict__ key,
                                                    const unsigned int* __restrict__ flag_list,
                                                    const unsigned int* __restrict__ flag_cnt,
                                                    unsigned int* __restrict__ idx) {
    int w = threadIdx.x >> 6, l = threadIdx.x & 63;
    unsigned total = flag_cnt[0];
    if (total > LISTCAP) total = LISTCAP;
    for (unsigned t = blockIdx.x * 4 + w; t < total; t += gridDim.x * 4) {
        unsigned e = flag_list[t];
        unsigned tok = e & 0x7FFFFu;
        int i1 = (int)((e >> 19) & 63u), i2 = (int)((e >> 25) & 63u);
        unsigned bh = tok >> 12;
        unsigned s = tok & 4095u;
        unsigned bb = bh / H_;
        int l32 = l & 31;
        const float* qrow = qk + ((size_t)bh * N_ + (l < 32 ? i1 : i2)) * C_ + l32 * 12;
        const float* krow = key + ((size_t)bb * S_ + s) * C_ + l32 * 12;
        float sum = 0.f;
#pragma unroll
        for (int c = 0; c < 12; ++c) sum += qrow[c] * krow[c];
#pragma unroll
        for (int off = 1; off < 32; off <<= 1) sum += __shfl_xor(sum, off);
        float d1 = __shfl(sum, 0);
        float d2 = __shfl(sum, 32);
        int win = (d2 > d1 || (d2 == d1 && i2 < i1)) ? i2 : i1;
        if (l == 0) idx[(size_t)bh * S_ + s] = (unsigned)win;
    }
}

// ---------------------------------------------------------------------------
// K4: scatter KEYS into group sums: gacc[b,h,g,c] = sum_{s: idx=g} khi[b,s,c]
// (v = key@Wv^T is linear, so group-sum commutes with the projection.)
// Grid (cchunk=3, h, b*4+schunk); lane=channel => coalesced 128B loads,
// LDS banks (g*129+ch)%32 = 2-way (free). Flush via global atomics.
// ---------------------------------------------------------------------------
__global__ __launch_bounds__(256) void scatter_kernel(const unsigned short* __restrict__ khi,
                                                      const unsigned int* __restrict__ idx,
                                                      float* __restrict__ gacc,
                                                      unsigned int* __restrict__ cnt) {
    __shared__ float accs[N_ * 129];     // 33 KB
    __shared__ unsigned int cnts[N_];
    int tid = threadIdx.x;
    int cchunk = blockIdx.x;
    int h = blockIdx.y;
    int b = blockIdx.z >> 2, schunk = blockIdx.z & 3;
    int c0 = cchunk * 128;
    for (int i = tid; i < N_ * 129; i += 256) accs[i] = 0.f;
    if (tid < N_) cnts[tid] = 0u;
    __syncthreads();
    int w = tid >> 6, l = tid & 63;
    int ch = (w & 1) * 64 + l;           // channel within chunk (0..127)
    int sphase = w >> 1;                 // 0 or 1
    bool do_cnt = (cchunk == 0) && ((w & 1) == 0) && (l == 0);
    int sbase = schunk * 1024;
    const unsigned int* idxp = idx + (size_t)(b * H_ + h) * S_;
    const unsigned short* kp = khi + (size_t)b * S_ * C_ + c0 + ch;
    for (int s8 = sbase + sphase; s8 < sbase + 1024; s8 += 16) {
        float v[8]; unsigned g[8];
#pragma unroll
        for (int i = 0; i < 8; ++i) {
            int s = s8 + 2 * i;
            g[i] = idxp[s];
            v[i] = bf2f(kp[(size_t)s * C_]);
        }
#pragma unroll
        for (int i = 0; i < 8; ++i) {
            atomicAdd(&accs[g[i] * 129 + ch], v[i]);
            if (do_cnt) atomicAdd(&cnts[g[i]], 1u);
        }
    }
    __syncthreads();
    float* gp = gacc + ((size_t)(b * H_ + h) * N_) * C_ + c0;
    for (int i = tid; i < N_ * 128; i += 256) {
        int g = i >> 7, cc = i & 127;
        float v = accs[g * 129 + cc];
        if (v != 0.f) atomicAdd(&gp[(size_t)g * C_ + cc], v);
    }
    if (cchunk == 0 && tid < N_) {
        unsigned c = cnts[tid];
        if (c) atomicAdd(&cnt[(size_t)(b * H_ + h) * N_ + tid], c);
    }
}

// ---------------------------------------------------------------------------
// K5: gv — tiny GEMM: gvn[b,h,g,d] = (gacc[b,h,g,:] . Wv[h*64+d,:]) / (cnt+1)
// ---------------------------------------------------------------------------
__global__ __launch_bounds__(256) void gv_kernel(const float* __restrict__ gacc,
                                                 const unsigned int* __restrict__ cnt,
                                                 const float* __restrict__ Wv,
                                                 float* __restrict__ gvn) {
    __shared__ float rows[4][C_ + 4];
    int h = blockIdx.x, b = blockIdx.y;
    int tid = threadIdx.x;
    int w = tid >> 6, l = tid & 63;
    const float* wrow = Wv + (size_t)(h * DH_ + l) * C_;
    for (int gs = 0; gs < 16; ++gs) {
        int g = gs * 4 + w;
        const float* src = gacc + ((size_t)(b * H_ + h) * N_ + g) * C_;
        for (int i = l; i < C_ / 4; i += 64)
            *(float4*)&rows[w][i * 4] = *(const float4*)&src[i * 4];
        // same-wave LDS write->read; compiler inserts lgkmcnt wait
        float acc = 0.f;
#pragma unroll 8
        for (int c4 = 0; c4 < C_ / 4; ++c4) {
            float4 a = *(float4*)&rows[w][c4 * 4];
            float4 wv = *(const float4*)&wrow[c4 * 4];
            acc += a.x * wv.x + a.y * wv.y + a.z * wv.z + a.w * wv.w;
        }
        float inv = 1.f / ((float)cnt[(size_t)(b * H_ + h) * N_ + g] + 1.f);
        gvn[((size_t)(b * H_ + h) * N_ + g) * DH_ + l] = acc * inv;
        __syncthreads();   // protect rows[w] reuse across gs (cheap, 16 iters)
    }
}

// ---------------------------------------------------------------------------
// K6: out[b,n,j] = sum_{h,d} gvn[b,h,n,d] * Wp[j, h*64+d] + bp[j]
// ---------------------------------------------------------------------------
__global__ __launch_bounds__(384) void out_kernel(const float* __restrict__ gvn,
                                                  const float* __restrict__ Wp,
                                                  const float* __restrict__ bp,
                                                  float* __restrict__ out) {
    __shared__ float vals[C_];
    int bn = blockIdx.x;
    int b = bn >> 6, n = bn & 63;
    int t = threadIdx.x;
    int h = t >> 6, d = t & 63;
    vals[t] = gvn[((size_t)(b * H_ + h) * N_ + n) * DH_ + d];
    __syncthreads();
    const float4* w4 = (const float4*)(Wp + (size_t)t * C_);
    const float4* v4 = (const float4*)vals;
    float s = bp[t];
#pragma unroll 8
    for (int i = 0; i < C_ / 4; ++i) {
        float4 a = v4[i]; float4 w = w4[i];
        s += a.x * w.x + a.y * w.y + a.z * w.z + a.w * w.w;
    }
    out[(size_t)bn * C_ + t] = s;
}

// ---------------------------------------------------------------------------
extern "C" void kernel_launch(void* const* d_in, const int* in_sizes, int n_in,
                              void* d_out, int out_size, void* d_ws, size_t ws_size,
                              hipStream_t stream) {
    (void)in_sizes; (void)n_in; (void)out_size; (void)ws_size;
    const float* query = (const float*)d_in[0];
    const float* key   = (const float*)d_in[1];
    const float* Wq    = (const float*)d_in[2];
    const float* Wk    = (const float*)d_in[3];
    const float* Wv    = (const float*)d_in[4];
    const float* Wp    = (const float*)d_in[5];
    const float* bp    = (const float*)d_in[6];
    float* out = (float*)d_out;

    char* ws = (char*)d_ws;
    size_t off = 0;
    unsigned short* khi  = (unsigned short*)(ws + off); off += (size_t)B_ * S_ * C_ * 2;      // 50.3 MB
    unsigned short* klo  = (unsigned short*)(ws + off); off += (size_t)B_ * S_ * C_ * 2;      // 50.3 MB
    float* qk            = (float*)(ws + off);          off += (size_t)B_ * H_ * N_ * C_ * 4; //  9.4 MB
    unsigned short* qkhi = (unsigned short*)(ws + off); off += (size_t)B_ * H_ * N_ * C_ * 2;
    unsigned short* qklo = (unsigned short*)(ws + off); off += (size_t)B_ * H_ * N_ * C_ * 2;
    unsigned int* idx    = (unsigned int*)(ws + off);   off += (size_t)B_ * H_ * S_ * 4;
    // --- contiguous zero-init region: gacc, cnt, fcnt ---
    float* gacc          = (float*)(ws + off);          off += (size_t)B_ * H_ * N_ * C_ * 4; //  9.4 MB
    unsigned int* cnt    = (unsigned int*)(ws + off);   off += (size_t)B_ * H_ * N_ * 4;
    unsigned int* fcnt   = (unsigned int*)(ws + off);   off += 256;
    // ----------------------------------------------------
    unsigned int* flist  = (unsigned int*)(ws + off);   off += (size_t)LISTCAP * 4;
    float* gvn           = (float*)(ws + off);          off += (size_t)B_ * H_ * N_ * DH_ * 4;

    size_t zbytes = (size_t)B_ * H_ * N_ * C_ * 4 + (size_t)B_ * H_ * N_ * 4 + 256;
    hipMemsetAsync(gacc, 0, zbytes, stream);

    prep_kernel<<<(B_ * S_ * C_ / 8) / 256, 256, 0, stream>>>(key, khi, klo);
    qk_fused_kernel<<<dim3(N_ / 8, B_), 384, 0, stream>>>(query, Wq, Wk, qk, qkhi, qklo);
    attn_kernel<<<dim3(S_ / 256, H_, B_), 256, 0, stream>>>(qkhi, qklo, khi, klo, idx, fcnt, flist);
    fixup_kernel<<<256, 256, 0, stream>>>(qk, key, flist, fcnt, idx);
    scatter_kernel<<<dim3(3, H_, B_ * 4), 256, 0, stream>>>(khi, idx, gacc, cnt);
    gv_kernel<<<dim3(H_, B_), 256, 0, stream>>>(gacc, cnt, Wv, gvn);
    out_kernel<<<B_ * N_, 384, 0, stream>>>(gvn, Wp, bp, out);
}

// Round 5
// 790.152 us; speedup vs baseline: 1.7939x; 1.7939x over previous
//
#include <hip/hip_runtime.h>
#include <hip/hip_bf16.h>
#include <stdint.h>

#define B_ 16
#define N_ 64
#define S_ 4096
#define C_ 384
#define H_ 6
#define DH_ 64
#define SCALE_ 0.125f
#define TAU_ 2e-4f
#define LISTCAP 262144

typedef __attribute__((ext_vector_type(8))) short bf16x8;
typedef __attribute__((ext_vector_type(4))) float f32x4;

static __device__ __forceinline__ unsigned short f2bf(float x) {
    union { float f; unsigned u; } v; v.f = x;
    unsigned r = v.u + 0x7FFFu + ((v.u >> 16) & 1u);
    return (unsigned short)(r >> 16);
}
static __device__ __forceinline__ float bf2f(unsigned short b) {
    union { unsigned u; float f; } v; v.u = ((unsigned)b) << 16; return v.f;
}

// async global->LDS, 16B/lane; LDS dest = wave-uniform base + lane*16
static __device__ __forceinline__ void gl_lds16(const void* g, void* l) {
    __builtin_amdgcn_global_load_lds(
        (const __attribute__((address_space(1))) unsigned int*)g,
        (__attribute__((address_space(3))) unsigned int*)l, 16, 0, 0);
}

// ---------------------------------------------------------------------------
// K0: prep — key -> khi/klo (bf16 hi + bf16 residual)
// ---------------------------------------------------------------------------
__global__ __launch_bounds__(256) void prep_kernel(const float* __restrict__ key,
                                                   unsigned short* __restrict__ khi,
                                                   unsigned short* __restrict__ klo) {
    size_t gid = (size_t)blockIdx.x * 256 + threadIdx.x;
    size_t base = gid * 8;
    float4 x0 = *(const float4*)(key + base);
    float4 x1 = *(const float4*)(key + base + 4);
    float xs[8] = { x0.x, x0.y, x0.z, x0.w, x1.x, x1.y, x1.z, x1.w };
    unsigned short hi[8], lo[8];
#pragma unroll
    for (int i = 0; i < 8; ++i) {
        hi[i] = f2bf(xs[i]);
        lo[i] = f2bf(xs[i] - bf2f(hi[i]));
    }
    *(bf16x8*)(khi + base) = *(bf16x8*)hi;
    *(bf16x8*)(klo + base) = *(bf16x8*)lo;
}

// ---------------------------------------------------------------------------
// K1: fused q-proj + qk (fp32 exact) + bf16 hi/lo split of qk
// ---------------------------------------------------------------------------
__global__ __launch_bounds__(384) void qk_fused_kernel(const float* __restrict__ query,
                                                       const float* __restrict__ Wq,
                                                       const float* __restrict__ Wk,
                                                       float* __restrict__ qk,
                                                       unsigned short* __restrict__ qkhi,
                                                       unsigned short* __restrict__ qklo) {
    __shared__ float qstage[8][C_];
    __shared__ float qrow[8][C_];
    int ng = blockIdx.x, b = blockIdx.y;
    int t = threadIdx.x;
    int n0 = ng * 8;
#pragma unroll
    for (int i = 0; i < 8; ++i)
        qstage[i][t] = query[((size_t)(b * N_ + n0 + i)) * C_ + t];
    __syncthreads();
    {
        float a[8];
#pragma unroll
        for (int i = 0; i < 8; ++i) a[i] = 0.f;
        const float4* wq = (const float4*)(Wq + (size_t)t * C_);
        for (int c4 = 0; c4 < C_ / 4; ++c4) {
            float4 w = wq[c4];
#pragma unroll
            for (int i = 0; i < 8; ++i)
                a[i] += qstage[i][c4 * 4 + 0] * w.x + qstage[i][c4 * 4 + 1] * w.y
                      + qstage[i][c4 * 4 + 2] * w.z + qstage[i][c4 * 4 + 3] * w.w;
        }
#pragma unroll
        for (int i = 0; i < 8; ++i) qrow[i][t] = a[i] * SCALE_;
    }
    __syncthreads();
    for (int h = 0; h < H_; ++h) {
        float a[8];
#pragma unroll
        for (int i = 0; i < 8; ++i) a[i] = 0.f;
        const float* wk = Wk + (size_t)h * DH_ * C_ + t;
#pragma unroll 4
        for (int d = 0; d < DH_; ++d) {
            float w = wk[(size_t)d * C_];
#pragma unroll
            for (int i = 0; i < 8; ++i) a[i] += qrow[i][h * DH_ + d] * w;
        }
#pragma unroll
        for (int i = 0; i < 8; ++i) {
            size_t o = ((size_t)(b * H_ + h) * N_ + n0 + i) * C_ + t;
            float v = a[i];
            qk[o] = v;
            unsigned short hi = f2bf(v);
            qkhi[o] = hi;
            qklo[o] = f2bf(v - bf2f(hi));
        }
    }
}

// ---------------------------------------------------------------------------
// K2: logits via 3-pass bf16 MFMA + argmax. 64n x 256 tokens,
// XOR-swizzled LDS quarters (conflicts measured 0 in round 3/4).
// ---------------------------------------------------------------------------
__global__ __launch_bounds__(256) void attn_kernel(const unsigned short* __restrict__ qkhi,
                                                   const unsigned short* __restrict__ qklo,
                                                   const unsigned short* __restrict__ khi,
                                                   const unsigned short* __restrict__ klo,
                                                   unsigned int* __restrict__ idx,
                                                   unsigned int* __restrict__ flag_cnt,
                                                   unsigned int* __restrict__ flag_list) {
    __shared__ __align__(16) unsigned short sAhi[64 * 32];
    __shared__ __align__(16) unsigned short sAlo[64 * 32];
    __shared__ __align__(16) unsigned short sBhi[256 * 32];
    __shared__ __align__(16) unsigned short sBlo[256 * 32];
    int tid = threadIdx.x;
    int w = tid >> 6, l = tid & 63;
    int wm = w >> 1, wn = w & 1;
    int q4 = l >> 4, lm = l & 15;
    int s0 = blockIdx.x * 256;
    int h = blockIdx.y, b = blockIdx.z;
    size_t kbK = ((size_t)b * S_ + s0) * C_;
    size_t kbA = (size_t)(b * H_ + h) * N_ * C_;
    int trow16 = l >> 2;
    int tquart = ((l & 3) ^ ((l >> 3) & 3)) * 8;   // swizzled source quarter
    int sw = (q4 ^ ((lm >> 1) & 3)) * 8;           // swizzled read quarter

    f32x4 acc[2][8];
#pragma unroll
    for (int tm = 0; tm < 2; ++tm)
#pragma unroll
        for (int nt = 0; nt < 8; ++nt) acc[tm][nt] = (f32x4)0.f;

    for (int kc = 0; kc < C_; kc += 32) {
        __syncthreads();
#pragma unroll
        for (int i = 0; i < 10; ++i) {
            int gid = w * 10 + i;
            if (gid < 16) {
                gl_lds16(khi + kbK + (size_t)(gid * 16 + trow16) * C_ + kc + tquart,
                         (char*)sBhi + gid * 1024);
            } else if (gid < 32) {
                int g2 = gid - 16;
                gl_lds16(klo + kbK + (size_t)(g2 * 16 + trow16) * C_ + kc + tquart,
                         (char*)sBlo + g2 * 1024);
            } else if (gid < 36) {
                int g2 = gid - 32;
                gl_lds16(qkhi + kbA + (size_t)(g2 * 16 + trow16) * C_ + kc + tquart,
                         (char*)sAhi + g2 * 1024);
            } else {
                int g2 = gid - 36;
                gl_lds16(qklo + kbA + (size_t)(g2 * 16 + trow16) * C_ + kc + tquart,
                         (char*)sAlo + g2 * 1024);
            }
        }
        __syncthreads();
        bf16x8 ah[2], al[2];
#pragma unroll
        for (int tm = 0; tm < 2; ++tm) {
            int ar = (wm * 32 + tm * 16 + lm) * 32 + sw;
            ah[tm] = *(const bf16x8*)&sAhi[ar];
            al[tm] = *(const bf16x8*)&sAlo[ar];
        }
#pragma unroll
        for (int nt = 0; nt < 8; ++nt) {
            int nr = ((wn * 8 + nt) * 16 + lm) * 32 + sw;
            bf16x8 bh = *(const bf16x8*)&sBhi[nr];
            bf16x8 bl = *(const bf16x8*)&sBlo[nr];
#pragma unroll
            for (int tm = 0; tm < 2; ++tm) {
                acc[tm][nt] = __builtin_amdgcn_mfma_f32_16x16x32_bf16(ah[tm], bh, acc[tm][nt], 0, 0, 0);
                acc[tm][nt] = __builtin_amdgcn_mfma_f32_16x16x32_bf16(ah[tm], bl, acc[tm][nt], 0, 0, 0);
                acc[tm][nt] = __builtin_amdgcn_mfma_f32_16x16x32_bf16(al[tm], bh, acc[tm][nt], 0, 0, 0);
            }
        }
    }
    __syncthreads();

    float* rm1 = (float*)sBhi;            // [2][256]
    float* rm2 = rm1 + 512;
    int* ri1 = (int*)(rm2 + 512);
    int* ri2 = ri1 + 512;

#pragma unroll
    for (int nt = 0; nt < 8; ++nt) {
        float m1 = -3.4e38f, m2 = -3.4e38f; int i1 = 0, i2 = 0;
#pragma unroll
        for (int tm = 0; tm < 2; ++tm)
#pragma unroll
            for (int r = 0; r < 4; ++r) {
                float v = acc[tm][nt][r];
                int row = wm * 32 + tm * 16 + q4 * 4 + r;
                if (v > m1) { m2 = m1; i2 = i1; m1 = v; i1 = row; }
                else if (v > m2) { m2 = v; i2 = row; }
            }
#pragma unroll
        for (int off = 16; off < 64; off <<= 1) {
            float om1 = __shfl_xor(m1, off), om2 = __shfl_xor(m2, off);
            int oi1 = __shfl_xor(i1, off), oi2 = __shfl_xor(i2, off);
            bool take = (om1 > m1) || (om1 == m1 && oi1 < i1);
            float w1 = take ? om1 : m1; int wi1 = take ? oi1 : i1;
            float l1 = take ? m1 : om1; int li1 = take ? i1 : oi1;
            float s2 = m2; int si2 = i2;
            if (om2 > s2) { s2 = om2; si2 = oi2; }
            if (l1 > s2) { s2 = l1; si2 = li1; }
            m1 = w1; i1 = wi1; m2 = s2; i2 = si2;
        }
        if (q4 == 0) {
            int cw = (wn * 8 + nt) * 16 + lm;
            rm1[wm * 256 + cw] = m1; rm2[wm * 256 + cw] = m2;
            ri1[wm * 256 + cw] = i1; ri2[wm * 256 + cw] = i2;
        }
    }
    __syncthreads();
    float a1 = rm1[tid], a2 = rm2[tid];
    int ai1 = ri1[tid], ai2 = ri2[tid];
    float b1 = rm1[256 + tid], b2 = rm2[256 + tid];
    int bi1 = ri1[256 + tid], bi2 = ri2[256 + tid];
    float w1, s2; int wi1, wi2;
    if (b1 > a1) { w1 = b1; wi1 = bi1; s2 = a1; wi2 = ai1; if (b2 > s2) { s2 = b2; wi2 = bi2; } }
    else         { w1 = a1; wi1 = ai1; s2 = a2; wi2 = ai2; if (b1 > s2) { s2 = b1; wi2 = bi1; } }
    idx[(size_t)(b * H_ + h) * S_ + s0 + tid] = (unsigned)wi1;
    if (w1 - s2 < TAU_) {
        unsigned p = atomicAdd(flag_cnt, 1u);
        if (p < LISTCAP) {
            unsigned tok = (unsigned)((b * H_ + h) * S_ + s0 + tid);
            flag_list[p] = tok | ((unsigned)wi1 << 19) | ((unsigned)wi2 << 25);
        }
    }
}

// ---------------------------------------------------------------------------
// K3: fixup — exact fp32 recompute of two candidate rows for near-ties
// ---------------------------------------------------------------------------
__global__ __launch_bounds__(256) void fixup_kernel(const float* __restrict__ qk,
                                                    const float* __restrict__ key,
                                                    const unsigned int* __restrict__ flag_list,
                                                    const unsigned int* __restrict__ flag_cnt,
                                                    unsigned int* __restrict__ idx) {
    int w = threadIdx.x >> 6, l = threadIdx.x & 63;
    unsigned total = flag_cnt[0];
    if (total > LISTCAP) total = LISTCAP;
    for (unsigned t = blockIdx.x * 4 + w; t < total; t += gridDim.x * 4) {
        unsigned e = flag_list[t];
        unsigned tok = e & 0x7FFFFu;
        int i1 = (int)((e >> 19) & 63u), i2 = (int)((e >> 25) & 63u);
        unsigned bh = tok >> 12;
        unsigned s = tok & 4095u;
        unsigned bb = bh / H_;
        int l32 = l & 31;
        const float* qrow = qk + ((size_t)bh * N_ + (l < 32 ? i1 : i2)) * C_ + l32 * 12;
        const float* krow = key + ((size_t)bb * S_ + s) * C_ + l32 * 12;
        float sum = 0.f;
#pragma unroll
        for (int c = 0; c < 12; ++c) sum += qrow[c] * krow[c];
#pragma unroll
        for (int off = 1; off < 32; off <<= 1) sum += __shfl_xor(sum, off);
        float d1 = __shfl(sum, 0);
        float d2 = __shfl(sum, 32);
        int win = (d2 > d1 || (d2 == d1 && i2 < i1)) ? i2 : i1;
        if (l == 0) idx[(size_t)bh * S_ + s] = (unsigned)win;
    }
}

// ---------------------------------------------------------------------------
// K4: agg — gacc[b,h,g,c] = sum_{s: idx=g} khi[b,s,c], NO atomics.
// Block = (cchunk 0..5, h, b). 4 waves, each with a PRIVATE 64g x 64ch fp32
// LDS accumulator (4 x 16 KB = 64 KB). Wave-uniform g, lane = channel;
// plain ds read-add-write RMW (in-order within a wave, private across waves).
// Banks: addr/4 % 32 = l%32 -> 2-way (free). Non-atomic gacc store (each
// block owns its (b,h,cchunk) slice exclusively) -> no memset needed.
// ---------------------------------------------------------------------------
__global__ __launch_bounds__(256) void agg_kernel(const unsigned short* __restrict__ khi,
                                                  const unsigned int* __restrict__ idx,
                                                  float* __restrict__ gacc) {
    __shared__ float accs[4][N_ * DH_];   // 64 KB
    int tid = threadIdx.x;
    int w = tid >> 6, l = tid & 63;
    int cchunk = blockIdx.x;
    int h = blockIdx.y;
    int b = blockIdx.z;
    {
        float4* z = (float4*)accs;
        for (int i = tid; i < 4 * N_ * DH_ / 4; i += 256) z[i] = float4{0.f, 0.f, 0.f, 0.f};
    }
    __syncthreads();
    const unsigned int* idxp = idx + (size_t)(b * H_ + h) * S_;
    const unsigned short* kp = khi + (size_t)b * S_ * C_ + cchunk * DH_ + l;
    float* ac = accs[w];
    int sbase = w * (S_ / 4);
#pragma unroll 1
    for (int s = sbase; s < sbase + S_ / 4; s += 4) {
        unsigned g0 = idxp[s + 0], g1 = idxp[s + 1], g2 = idxp[s + 2], g3 = idxp[s + 3];
        float v0 = bf2f(kp[(size_t)(s + 0) * C_]);
        float v1 = bf2f(kp[(size_t)(s + 1) * C_]);
        float v2 = bf2f(kp[(size_t)(s + 2) * C_]);
        float v3 = bf2f(kp[(size_t)(s + 3) * C_]);
        ac[g0 * DH_ + l] += v0;
        ac[g1 * DH_ + l] += v1;
        ac[g2 * DH_ + l] += v2;
        ac[g3 * DH_ + l] += v3;
    }
    __syncthreads();
    float* gp = gacc + ((size_t)(b * H_ + h) * N_) * C_ + cchunk * DH_;
    for (int i = tid; i < N_ * DH_; i += 256) {
        int g = i >> 6, d = i & 63;
        float v = accs[0][i] + accs[1][i] + accs[2][i] + accs[3][i];
        gp[(size_t)g * C_ + d] = v;
    }
}

// ---------------------------------------------------------------------------
// K5: cnt — integer histogram of idx per (b,h). ds_add_u32 is native.
// ---------------------------------------------------------------------------
__global__ __launch_bounds__(256) void cnt_kernel(const unsigned int* __restrict__ idx,
                                                  unsigned int* __restrict__ cnt) {
    __shared__ unsigned int cnts[N_];
    int tid = threadIdx.x;
    int h = blockIdx.x, b = blockIdx.y;
    if (tid < N_) cnts[tid] = 0u;
    __syncthreads();
    const unsigned int* idxp = idx + (size_t)(b * H_ + h) * S_;
    for (int s = tid; s < S_; s += 256) atomicAdd(&cnts[idxp[s]], 1u);
    __syncthreads();
    if (tid < N_) cnt[(size_t)(b * H_ + h) * N_ + tid] = cnts[tid];
}

// ---------------------------------------------------------------------------
// K6: gv — tiny GEMM: gvn[b,h,g,d] = (gacc[b,h,g,:] . Wv[h*64+d,:]) / (cnt+1)
// ---------------------------------------------------------------------------
__global__ __launch_bounds__(256) void gv_kernel(const float* __restrict__ gacc,
                                                 const unsigned int* __restrict__ cnt,
                                                 const float* __restrict__ Wv,
                                                 float* __restrict__ gvn) {
    __shared__ float rows[4][C_ + 4];
    int h = blockIdx.x, b = blockIdx.y;
    int tid = threadIdx.x;
    int w = tid >> 6, l = tid & 63;
    const float* wrow = Wv + (size_t)(h * DH_ + l) * C_;
    for (int gs = 0; gs < 16; ++gs) {
        int g = gs * 4 + w;
        const float* src = gacc + ((size_t)(b * H_ + h) * N_ + g) * C_;
        for (int i = l; i < C_ / 4; i += 64)
            *(float4*)&rows[w][i * 4] = *(const float4*)&src[i * 4];
        float acc = 0.f;
#pragma unroll 8
        for (int c4 = 0; c4 < C_ / 4; ++c4) {
            float4 a = *(float4*)&rows[w][c4 * 4];
            float4 wv = *(const float4*)&wrow[c4 * 4];
            acc += a.x * wv.x + a.y * wv.y + a.z * wv.z + a.w * wv.w;
        }
        float inv = 1.f / ((float)cnt[(size_t)(b * H_ + h) * N_ + g] + 1.f);
        gvn[((size_t)(b * H_ + h) * N_ + g) * DH_ + l] = acc * inv;
        __syncthreads();
    }
}

// ---------------------------------------------------------------------------
// K7: out[b,n,j] = sum_{h,d} gvn[b,h,n,d] * Wp[j, h*64+d] + bp[j]
// ---------------------------------------------------------------------------
__global__ __launch_bounds__(384) void out_kernel(const float* __restrict__ gvn,
                                                  const float* __restrict__ Wp,
                                                  const float* __restrict__ bp,
                                                  float* __restrict__ out) {
    __shared__ float vals[C_];
    int bn = blockIdx.x;
    int b = bn >> 6, n = bn & 63;
    int t = threadIdx.x;
    int h = t >> 6, d = t & 63;
    vals[t] = gvn[((size_t)(b * H_ + h) * N_ + n) * DH_ + d];
    __syncthreads();
    const float4* w4 = (const float4*)(Wp + (size_t)t * C_);
    const float4* v4 = (const float4*)vals;
    float s = bp[t];
#pragma unroll 8
    for (int i = 0; i < C_ / 4; ++i) {
        float4 a = v4[i]; float4 w = w4[i];
        s += a.x * w.x + a.y * w.y + a.z * w.z + a.w * w.w;
    }
    out[(size_t)bn * C_ + t] = s;
}

// ---------------------------------------------------------------------------
extern "C" void kernel_launch(void* const* d_in, const int* in_sizes, int n_in,
                              void* d_out, int out_size, void* d_ws, size_t ws_size,
                              hipStream_t stream) {
    (void)in_sizes; (void)n_in; (void)out_size; (void)ws_size;
    const float* query = (const float*)d_in[0];
    const float* key   = (const float*)d_in[1];
    const float* Wq    = (const float*)d_in[2];
    const float* Wk    = (const float*)d_in[3];
    const float* Wv    = (const float*)d_in[4];
    const float* Wp    = (const float*)d_in[5];
    const float* bp    = (const float*)d_in[6];
    float* out = (float*)d_out;

    char* ws = (char*)d_ws;
    size_t off = 0;
    unsigned short* khi  = (unsigned short*)(ws + off); off += (size_t)B_ * S_ * C_ * 2;      // 50.3 MB
    unsigned short* klo  = (unsigned short*)(ws + off); off += (size_t)B_ * S_ * C_ * 2;      // 50.3 MB
    float* qk            = (float*)(ws + off);          off += (size_t)B_ * H_ * N_ * C_ * 4; //  9.4 MB
    unsigned short* qkhi = (unsigned short*)(ws + off); off += (size_t)B_ * H_ * N_ * C_ * 2;
    unsigned short* qklo = (unsigned short*)(ws + off); off += (size_t)B_ * H_ * N_ * C_ * 2;
    unsigned int* idx    = (unsigned int*)(ws + off);   off += (size_t)B_ * H_ * S_ * 4;
    float* gacc          = (float*)(ws + off);          off += (size_t)B_ * H_ * N_ * C_ * 4; //  9.4 MB
    unsigned int* cnt    = (unsigned int*)(ws + off);   off += (size_t)B_ * H_ * N_ * 4;
    unsigned int* fcnt   = (unsigned int*)(ws + off);   off += 256;
    unsigned int* flist  = (unsigned int*)(ws + off);   off += (size_t)LISTCAP * 4;
    float* gvn           = (float*)(ws + off);          off += (size_t)B_ * H_ * N_ * DH_ * 4;

    hipMemsetAsync(fcnt, 0, 256, stream);   // only the flag counter needs zeroing

    prep_kernel<<<(B_ * S_ * C_ / 8) / 256, 256, 0, stream>>>(key, khi, klo);
    qk_fused_kernel<<<dim3(N_ / 8, B_), 384, 0, stream>>>(query, Wq, Wk, qk, qkhi, qklo);
    attn_kernel<<<dim3(S_ / 256, H_, B_), 256, 0, stream>>>(qkhi, qklo, khi, klo, idx, fcnt, flist);
    fixup_kernel<<<256, 256, 0, stream>>>(qk, key, flist, fcnt, idx);
    agg_kernel<<<dim3(C_ / DH_, H_, B_), 256, 0, stream>>>(khi, idx, gacc);
    cnt_kernel<<<dim3(H_, B_), 256, 0, stream>>>(idx, cnt);
    gv_kernel<<<dim3(H_, B_), 256, 0, stream>>>(gacc, cnt, Wv, gvn);
    out_kernel<<<B_ * N_, 384, 0, stream>>>(gvn, Wp, bp, out);
}

// Round 6
// 662.030 us; speedup vs baseline: 2.1411x; 1.1935x over previous
//
#include <hip/hip_runtime.h>
#include <hip/hip_bf16.h>
#include <stdint.h>

#define B_ 16
#define N_ 64
#define S_ 4096
#define C_ 384
#define H_ 6
#define DH_ 64
#define SCALE_ 0.125f
#define TAU_ 2e-4f
#define LISTCAP 262144

typedef __attribute__((ext_vector_type(8))) short bf16x8;
typedef __attribute__((ext_vector_type(4))) float f32x4;

static __device__ __forceinline__ unsigned short f2bf(float x) {
    union { float f; unsigned u; } v; v.f = x;
    unsigned r = v.u + 0x7FFFu + ((v.u >> 16) & 1u);
    return (unsigned short)(r >> 16);
}
static __device__ __forceinline__ float bf2f(unsigned short b) {
    union { unsigned u; float f; } v; v.u = ((unsigned)b) << 16; return v.f;
}
static __device__ __forceinline__ float bfu_lo(unsigned u) {
    union { unsigned u; float f; } v; v.u = u << 16; return v.f;
}
static __device__ __forceinline__ float bfu_hi(unsigned u) {
    union { unsigned u; float f; } v; v.u = u & 0xFFFF0000u; return v.f;
}

// async global->LDS, 16B/lane; LDS dest = wave-uniform base + lane*16
static __device__ __forceinline__ void gl_lds16(const void* g, void* l) {
    __builtin_amdgcn_global_load_lds(
        (const __attribute__((address_space(1))) unsigned int*)g,
        (__attribute__((address_space(3))) unsigned int*)l, 16, 0, 0);
}

// ---------------------------------------------------------------------------
// K0: prep — key -> khi/klo (bf16 hi + bf16 residual)
// ---------------------------------------------------------------------------
__global__ __launch_bounds__(256) void prep_kernel(const float* __restrict__ key,
                                                   unsigned short* __restrict__ khi,
                                                   unsigned short* __restrict__ klo) {
    size_t gid = (size_t)blockIdx.x * 256 + threadIdx.x;
    size_t base = gid * 8;
    float4 x0 = *(const float4*)(key + base);
    float4 x1 = *(const float4*)(key + base + 4);
    float xs[8] = { x0.x, x0.y, x0.z, x0.w, x1.x, x1.y, x1.z, x1.w };
    unsigned short hi[8], lo[8];
#pragma unroll
    for (int i = 0; i < 8; ++i) {
        hi[i] = f2bf(xs[i]);
        lo[i] = f2bf(xs[i] - bf2f(hi[i]));
    }
    *(bf16x8*)(khi + base) = *(bf16x8*)hi;
    *(bf16x8*)(klo + base) = *(bf16x8*)lo;
}

// ---------------------------------------------------------------------------
// K1: fused q-proj + qk (fp32 exact) + bf16 hi/lo split. 4 rows/block,
// 256 blocks (round-5 used 128 blocks = half the CUs idle).
// ---------------------------------------------------------------------------
__global__ __launch_bounds__(384) void qk_fused_kernel(const float* __restrict__ query,
                                                       const float* __restrict__ Wq,
                                                       const float* __restrict__ Wk,
                                                       float* __restrict__ qk,
                                                       unsigned short* __restrict__ qkhi,
                                                       unsigned short* __restrict__ qklo) {
    __shared__ float qstage[4][C_];
    __shared__ float qrow[4][C_];
    int ng = blockIdx.x, b = blockIdx.y;
    int t = threadIdx.x;
    int n0 = ng * 4;
#pragma unroll
    for (int i = 0; i < 4; ++i)
        qstage[i][t] = query[((size_t)(b * N_ + n0 + i)) * C_ + t];
    __syncthreads();
    {
        float a[4];
#pragma unroll
        for (int i = 0; i < 4; ++i) a[i] = 0.f;
        const float4* wq = (const float4*)(Wq + (size_t)t * C_);
        for (int c4 = 0; c4 < C_ / 4; ++c4) {
            float4 w = wq[c4];
#pragma unroll
            for (int i = 0; i < 4; ++i)
                a[i] += qstage[i][c4 * 4 + 0] * w.x + qstage[i][c4 * 4 + 1] * w.y
                      + qstage[i][c4 * 4 + 2] * w.z + qstage[i][c4 * 4 + 3] * w.w;
        }
#pragma unroll
        for (int i = 0; i < 4; ++i) qrow[i][t] = a[i] * SCALE_;
    }
    __syncthreads();
    for (int h = 0; h < H_; ++h) {
        float a[4];
#pragma unroll
        for (int i = 0; i < 4; ++i) a[i] = 0.f;
        const float* wk = Wk + (size_t)h * DH_ * C_ + t;
#pragma unroll 4
        for (int d = 0; d < DH_; ++d) {
            float w = wk[(size_t)d * C_];
#pragma unroll
            for (int i = 0; i < 4; ++i) a[i] += qrow[i][h * DH_ + d] * w;
        }
#pragma unroll
        for (int i = 0; i < 4; ++i) {
            size_t o = ((size_t)(b * H_ + h) * N_ + n0 + i) * C_ + t;
            float v = a[i];
            qk[o] = v;
            unsigned short hi = f2bf(v);
            qkhi[o] = hi;
            qklo[o] = f2bf(v - bf2f(hi));
        }
    }
}

// ---------------------------------------------------------------------------
// K2: logits via 3-pass bf16 MFMA + argmax. 64n x 256 tokens,
// XOR-swizzled LDS quarters (conflicts measured 0). UNCHANGED (known-good).
// ---------------------------------------------------------------------------
__global__ __launch_bounds__(256) void attn_kernel(const unsigned short* __restrict__ qkhi,
                                                   const unsigned short* __restrict__ qklo,
                                                   const unsigned short* __restrict__ khi,
                                                   const unsigned short* __restrict__ klo,
                                                   unsigned int* __restrict__ idx,
                                                   unsigned int* __restrict__ flag_cnt,
                                                   unsigned int* __restrict__ flag_list) {
    __shared__ __align__(16) unsigned short sAhi[64 * 32];
    __shared__ __align__(16) unsigned short sAlo[64 * 32];
    __shared__ __align__(16) unsigned short sBhi[256 * 32];
    __shared__ __align__(16) unsigned short sBlo[256 * 32];
    int tid = threadIdx.x;
    int w = tid >> 6, l = tid & 63;
    int wm = w >> 1, wn = w & 1;
    int q4 = l >> 4, lm = l & 15;
    int s0 = blockIdx.x * 256;
    int h = blockIdx.y, b = blockIdx.z;
    size_t kbK = ((size_t)b * S_ + s0) * C_;
    size_t kbA = (size_t)(b * H_ + h) * N_ * C_;
    int trow16 = l >> 2;
    int tquart = ((l & 3) ^ ((l >> 3) & 3)) * 8;
    int sw = (q4 ^ ((lm >> 1) & 3)) * 8;

    f32x4 acc[2][8];
#pragma unroll
    for (int tm = 0; tm < 2; ++tm)
#pragma unroll
        for (int nt = 0; nt < 8; ++nt) acc[tm][nt] = (f32x4)0.f;

    for (int kc = 0; kc < C_; kc += 32) {
        __syncthreads();
#pragma unroll
        for (int i = 0; i < 10; ++i) {
            int gid = w * 10 + i;
            if (gid < 16) {
                gl_lds16(khi + kbK + (size_t)(gid * 16 + trow16) * C_ + kc + tquart,
                         (char*)sBhi + gid * 1024);
            } else if (gid < 32) {
                int g2 = gid - 16;
                gl_lds16(klo + kbK + (size_t)(g2 * 16 + trow16) * C_ + kc + tquart,
                         (char*)sBlo + g2 * 1024);
            } else if (gid < 36) {
                int g2 = gid - 32;
                gl_lds16(qkhi + kbA + (size_t)(g2 * 16 + trow16) * C_ + kc + tquart,
                         (char*)sAhi + g2 * 1024);
            } else {
                int g2 = gid - 36;
                gl_lds16(qklo + kbA + (size_t)(g2 * 16 + trow16) * C_ + kc + tquart,
                         (char*)sAlo + g2 * 1024);
            }
        }
        __syncthreads();
        bf16x8 ah[2], al[2];
#pragma unroll
        for (int tm = 0; tm < 2; ++tm) {
            int ar = (wm * 32 + tm * 16 + lm) * 32 + sw;
            ah[tm] = *(const bf16x8*)&sAhi[ar];
            al[tm] = *(const bf16x8*)&sAlo[ar];
        }
#pragma unroll
        for (int nt = 0; nt < 8; ++nt) {
            int nr = ((wn * 8 + nt) * 16 + lm) * 32 + sw;
            bf16x8 bh = *(const bf16x8*)&sBhi[nr];
            bf16x8 bl = *(const bf16x8*)&sBlo[nr];
#pragma unroll
            for (int tm = 0; tm < 2; ++tm) {
                acc[tm][nt] = __builtin_amdgcn_mfma_f32_16x16x32_bf16(ah[tm], bh, acc[tm][nt], 0, 0, 0);
                acc[tm][nt] = __builtin_amdgcn_mfma_f32_16x16x32_bf16(ah[tm], bl, acc[tm][nt], 0, 0, 0);
                acc[tm][nt] = __builtin_amdgcn_mfma_f32_16x16x32_bf16(al[tm], bh, acc[tm][nt], 0, 0, 0);
            }
        }
    }
    __syncthreads();

    float* rm1 = (float*)sBhi;
    float* rm2 = rm1 + 512;
    int* ri1 = (int*)(rm2 + 512);
    int* ri2 = ri1 + 512;

#pragma unroll
    for (int nt = 0; nt < 8; ++nt) {
        float m1 = -3.4e38f, m2 = -3.4e38f; int i1 = 0, i2 = 0;
#pragma unroll
        for (int tm = 0; tm < 2; ++tm)
#pragma unroll
            for (int r = 0; r < 4; ++r) {
                float v = acc[tm][nt][r];
                int row = wm * 32 + tm * 16 + q4 * 4 + r;
                if (v > m1) { m2 = m1; i2 = i1; m1 = v; i1 = row; }
                else if (v > m2) { m2 = v; i2 = row; }
            }
#pragma unroll
        for (int off = 16; off < 64; off <<= 1) {
            float om1 = __shfl_xor(m1, off), om2 = __shfl_xor(m2, off);
            int oi1 = __shfl_xor(i1, off), oi2 = __shfl_xor(i2, off);
            bool take = (om1 > m1) || (om1 == m1 && oi1 < i1);
            float w1 = take ? om1 : m1; int wi1 = take ? oi1 : i1;
            float l1 = take ? m1 : om1; int li1 = take ? i1 : oi1;
            float s2 = m2; int si2 = i2;
            if (om2 > s2) { s2 = om2; si2 = oi2; }
            if (l1 > s2) { s2 = l1; si2 = li1; }
            m1 = w1; i1 = wi1; m2 = s2; i2 = si2;
        }
        if (q4 == 0) {
            int cw = (wn * 8 + nt) * 16 + lm;
            rm1[wm * 256 + cw] = m1; rm2[wm * 256 + cw] = m2;
            ri1[wm * 256 + cw] = i1; ri2[wm * 256 + cw] = i2;
        }
    }
    __syncthreads();
    float a1 = rm1[tid], a2 = rm2[tid];
    int ai1 = ri1[tid], ai2 = ri2[tid];
    float b1 = rm1[256 + tid], b2 = rm2[256 + tid];
    int bi1 = ri1[256 + tid], bi2 = ri2[256 + tid];
    float w1, s2; int wi1, wi2;
    if (b1 > a1) { w1 = b1; wi1 = bi1; s2 = a1; wi2 = ai1; if (b2 > s2) { s2 = b2; wi2 = bi2; } }
    else         { w1 = a1; wi1 = ai1; s2 = a2; wi2 = ai2; if (b1 > s2) { s2 = b1; wi2 = bi1; } }
    idx[(size_t)(b * H_ + h) * S_ + s0 + tid] = (unsigned)wi1;
    if (w1 - s2 < TAU_) {
        unsigned p = atomicAdd(flag_cnt, 1u);
        if (p < LISTCAP) {
            unsigned tok = (unsigned)((b * H_ + h) * S_ + s0 + tid);
            flag_list[p] = tok | ((unsigned)wi1 << 19) | ((unsigned)wi2 << 25);
        }
    }
}

// ---------------------------------------------------------------------------
// K3: fixup — exact fp32 recompute of two candidate rows for near-ties
// ---------------------------------------------------------------------------
__global__ __launch_bounds__(256) void fixup_kernel(const float* __restrict__ qk,
                                                    const float* __restrict__ key,
                                                    const unsigned int* __restrict__ flag_list,
                                                    const unsigned int* __restrict__ flag_cnt,
                                                    unsigned int* __restrict__ idx) {
    int w = threadIdx.x >> 6, l = threadIdx.x & 63;
    unsigned total = flag_cnt[0];
    if (total > LISTCAP) total = LISTCAP;
    for (unsigned t = blockIdx.x * 4 + w; t < total; t += gridDim.x * 4) {
        unsigned e = flag_list[t];
        unsigned tok = e & 0x7FFFFu;
        int i1 = (int)((e >> 19) & 63u), i2 = (int)((e >> 25) & 63u);
        unsigned bh = tok >> 12;
        unsigned s = tok & 4095u;
        unsigned bb = bh / H_;
        int l32 = l & 31;
        const float* qrow = qk + ((size_t)bh * N_ + (l < 32 ? i1 : i2)) * C_ + l32 * 12;
        const float* krow = key + ((size_t)bb * S_ + s) * C_ + l32 * 12;
        float sum = 0.f;
#pragma unroll
        for (int c = 0; c < 12; ++c) sum += qrow[c] * krow[c];
#pragma unroll
        for (int off = 1; off < 32; off <<= 1) sum += __shfl_xor(sum, off);
        float d1 = __shfl(sum, 0);
        float d2 = __shfl(sum, 32);
        int win = (d2 > d1 || (d2 == d1 && i2 < i1)) ? i2 : i1;
        if (l == 0) idx[(size_t)bh * S_ + s] = (unsigned)win;
    }
}

// ---------------------------------------------------------------------------
// K4: hist_build — per (b,h): histogram of idx -> exclusive scan -> offs[65],
// then counting-sort placement: order[pos]=s. Native u32 LDS atomics only.
// ---------------------------------------------------------------------------
__global__ __launch_bounds__(256) void hist_build_kernel(const unsigned int* __restrict__ idx,
                                                         unsigned int* __restrict__ offs,
                                                         unsigned int* __restrict__ order) {
    __shared__ unsigned int cnts[N_];
    __shared__ unsigned int pos[N_];
    int tid = threadIdx.x;
    int bh = blockIdx.x;
    if (tid < N_) cnts[tid] = 0u;
    __syncthreads();
    const unsigned int* idxp = idx + (size_t)bh * S_;
    for (int s = tid; s < S_; s += 256) atomicAdd(&cnts[idxp[s]], 1u);
    __syncthreads();
    if (tid < N_) {
        unsigned v = cnts[tid];
        unsigned x = v;
#pragma unroll
        for (int off = 1; off < 64; off <<= 1) {
            unsigned y = __shfl_up(x, off);
            if (tid >= off) x += y;
        }
        unsigned excl = x - v;
        pos[tid] = excl;
        offs[(size_t)bh * 65 + tid] = excl;
        if (tid == 63) offs[(size_t)bh * 65 + 64] = x;   // == S_
    }
    __syncthreads();
    unsigned int* op = order + (size_t)bh * S_;
    for (int s = tid; s < S_; s += 256) {
        unsigned g = idxp[s];
        unsigned p = atomicAdd(&pos[g], 1u);
        op[p] = (unsigned)s;
    }
}

// ---------------------------------------------------------------------------
// K5: agg2 — per (group, half): contiguous token list -> pure register
// accumulation (6 fp32/lane), zero LDS in hot loop, 1/(cnt+1) folded in.
// gpart[(bh*2+part)*N + g][384]. Grid dim3(32, H, B), 4 waves/block.
// ---------------------------------------------------------------------------
__global__ __launch_bounds__(256) void agg2_kernel(const unsigned short* __restrict__ khi,
                                                   const unsigned int* __restrict__ order,
                                                   const unsigned int* __restrict__ offs,
                                                   float* __restrict__ gpart) {
    int tid = threadIdx.x;
    int w = tid >> 6, l = tid & 63;
    int h = blockIdx.y, b = blockIdx.z;
    int bh = b * H_ + h;
    int wid = blockIdx.x * 4 + w;       // 0..127
    int g = wid >> 1, part = wid & 1;
    unsigned beg = offs[(size_t)bh * 65 + g];
    unsigned end = offs[(size_t)bh * 65 + g + 1];
    int cnt = (int)(end - beg);
    float inv = 1.f / ((float)cnt + 1.f);
    const unsigned int* op = order + (size_t)bh * S_ + beg;
    const unsigned int* kbase = (const unsigned int*)(khi + (size_t)b * S_ * C_);
    float a0 = 0.f, a1 = 0.f, a2 = 0.f, a3 = 0.f, a4 = 0.f, a5 = 0.f;
    for (int base = part * 64; base < cnt; base += 128) {
        int m = cnt - base; if (m > 64) m = 64;
        unsigned sv = (l < m) ? op[base + l] : 0u;
        for (int i = 0; i < m; ++i) {
            int s = (int)__shfl((int)sv, i);
            const unsigned int* kp = kbase + (size_t)s * (C_ / 2) + l * 3;
            unsigned u0 = kp[0], u1 = kp[1], u2 = kp[2];
            a0 += bfu_lo(u0); a1 += bfu_hi(u0);
            a2 += bfu_lo(u1); a3 += bfu_hi(u1);
            a4 += bfu_lo(u2); a5 += bfu_hi(u2);
        }
    }
    float* gp = gpart + (((size_t)bh * 2 + part) * N_ + g) * C_ + l * 6;
    float2 o0 = { a0 * inv, a1 * inv };
    float2 o1 = { a2 * inv, a3 * inv };
    float2 o2 = { a4 * inv, a5 * inv };
    ((float2*)gp)[0] = o0; ((float2*)gp)[1] = o1; ((float2*)gp)[2] = o2;
}

// ---------------------------------------------------------------------------
// K6: gv — gvn[b,h,g,d] = (gpart0+gpart1)[b,h,g,:] . Wv[h*64+d,:]
// (inv already applied in agg2)
// ---------------------------------------------------------------------------
__global__ __launch_bounds__(256) void gv_kernel(const float* __restrict__ gpart,
                                                 const float* __restrict__ Wv,
                                                 float* __restrict__ gvn) {
    __shared__ float rows[4][C_ + 4];
    int h = blockIdx.x, b = blockIdx.y;
    int bh = b * H_ + h;
    int tid = threadIdx.x;
    int w = tid >> 6, l = tid & 63;
    const float* wrow = Wv + (size_t)(h * DH_ + l) * C_;
    for (int gs = 0; gs < 16; ++gs) {
        int g = gs * 4 + w;
        const float* s0 = gpart + (((size_t)bh * 2 + 0) * N_ + g) * C_;
        const float* s1 = gpart + (((size_t)bh * 2 + 1) * N_ + g) * C_;
        for (int i = l; i < C_ / 4; i += 64) {
            float4 x = *(const float4*)&s0[i * 4];
            float4 y = *(const float4*)&s1[i * 4];
            float4 z = { x.x + y.x, x.y + y.y, x.z + y.z, x.w + y.w };
            *(float4*)&rows[w][i * 4] = z;
        }
        float acc = 0.f;
#pragma unroll 8
        for (int c4 = 0; c4 < C_ / 4; ++c4) {
            float4 a = *(float4*)&rows[w][c4 * 4];
            float4 wv = *(const float4*)&wrow[c4 * 4];
            acc += a.x * wv.x + a.y * wv.y + a.z * wv.z + a.w * wv.w;
        }
        gvn[((size_t)bh * N_ + g) * DH_ + l] = acc;
        __syncthreads();
    }
}

// ---------------------------------------------------------------------------
// K7: out[b,n,j] = sum_{h,d} gvn[b,h,n,d] * Wp[j, h*64+d] + bp[j]
// ---------------------------------------------------------------------------
__global__ __launch_bounds__(384) void out_kernel(const float* __restrict__ gvn,
                                                  const float* __restrict__ Wp,
                                                  const float* __restrict__ bp,
                                                  float* __restrict__ out) {
    __shared__ float vals[C_];
    int bn = blockIdx.x;
    int b = bn >> 6, n = bn & 63;
    int t = threadIdx.x;
    int h = t >> 6, d = t & 63;
    vals[t] = gvn[((size_t)(b * H_ + h) * N_ + n) * DH_ + d];
    __syncthreads();
    const float4* w4 = (const float4*)(Wp + (size_t)t * C_);
    const float4* v4 = (const float4*)vals;
    float s = bp[t];
#pragma unroll 8
    for (int i = 0; i < C_ / 4; ++i) {
        float4 a = v4[i]; float4 w = w4[i];
        s += a.x * w.x + a.y * w.y + a.z * w.z + a.w * w.w;
    }
    out[(size_t)bn * C_ + t] = s;
}

// ---------------------------------------------------------------------------
extern "C" void kernel_launch(void* const* d_in, const int* in_sizes, int n_in,
                              void* d_out, int out_size, void* d_ws, size_t ws_size,
                              hipStream_t stream) {
    (void)in_sizes; (void)n_in; (void)out_size; (void)ws_size;
    const float* query = (const float*)d_in[0];
    const float* key   = (const float*)d_in[1];
    const float* Wq    = (const float*)d_in[2];
    const float* Wk    = (const float*)d_in[3];
    const float* Wv    = (const float*)d_in[4];
    const float* Wp    = (const float*)d_in[5];
    const float* bp    = (const float*)d_in[6];
    float* out = (float*)d_out;

    char* ws = (char*)d_ws;
    size_t off = 0;
    unsigned short* khi  = (unsigned short*)(ws + off); off += (size_t)B_ * S_ * C_ * 2;          // 50.3 MB
    unsigned short* klo  = (unsigned short*)(ws + off); off += (size_t)B_ * S_ * C_ * 2;          // 50.3 MB
    float* qk            = (float*)(ws + off);          off += (size_t)B_ * H_ * N_ * C_ * 4;     //  9.4 MB
    unsigned short* qkhi = (unsigned short*)(ws + off); off += (size_t)B_ * H_ * N_ * C_ * 2;
    unsigned short* qklo = (unsigned short*)(ws + off); off += (size_t)B_ * H_ * N_ * C_ * 2;
    unsigned int* idx    = (unsigned int*)(ws + off);   off += (size_t)B_ * H_ * S_ * 4;          //  1.6 MB
    unsigned int* order  = (unsigned int*)(ws + off);   off += (size_t)B_ * H_ * S_ * 4;          //  1.6 MB
    unsigned int* offs   = (unsigned int*)(ws + off);   off += (size_t)B_ * H_ * 65 * 4;
    float* gpart         = (float*)(ws + off);          off += (size_t)B_ * H_ * 2 * N_ * C_ * 4; // 18.9 MB
    float* gvn           = (float*)(ws + off);          off += (size_t)B_ * H_ * N_ * DH_ * 4;
    unsigned int* fcnt   = (unsigned int*)(ws + off);   off += 256;
    unsigned int* flist  = (unsigned int*)(ws + off);   off += (size_t)LISTCAP * 4;

    hipMemsetAsync(fcnt, 0, 256, stream);   // only the flag counter needs zeroing

    prep_kernel<<<(B_ * S_ * C_ / 8) / 256, 256, 0, stream>>>(key, khi, klo);
    qk_fused_kernel<<<dim3(N_ / 4, B_), 384, 0, stream>>>(query, Wq, Wk, qk, qkhi, qklo);
    attn_kernel<<<dim3(S_ / 256, H_, B_), 256, 0, stream>>>(qkhi, qklo, khi, klo, idx, fcnt, flist);
    fixup_kernel<<<256, 256, 0, stream>>>(qk, key, flist, fcnt, idx);
    hist_build_kernel<<<B_ * H_, 256, 0, stream>>>(idx, offs, order);
    agg2_kernel<<<dim3(32, H_, B_), 256, 0, stream>>>(khi, order, offs, gpart);
    gv_kernel<<<dim3(H_, B_), 256, 0, stream>>>(gpart, Wv, gvn);
    out_kernel<<<B_ * N_, 384, 0, stream>>>(gvn, Wp, bp, out);
}

// Round 7
// 546.043 us; speedup vs baseline: 2.5959x; 1.2124x over previous
//
#include <hip/hip_runtime.h>
#include <hip/hip_bf16.h>
#include <stdint.h>

#define B_ 16
#define N_ 64
#define S_ 4096
#define C_ 384
#define H_ 6
#define DH_ 64
#define SCALE_ 0.125f
#define TAU_ 2e-4f
#define LISTCAP 262144

typedef __attribute__((ext_vector_type(8))) short bf16x8;
typedef __attribute__((ext_vector_type(4))) float f32x4;

static __device__ __forceinline__ unsigned short f2bf(float x) {
    union { float f; unsigned u; } v; v.f = x;
    unsigned r = v.u + 0x7FFFu + ((v.u >> 16) & 1u);
    return (unsigned short)(r >> 16);
}
static __device__ __forceinline__ float bf2f(unsigned short b) {
    union { unsigned u; float f; } v; v.u = ((unsigned)b) << 16; return v.f;
}
static __device__ __forceinline__ float bfu_lo(unsigned u) {
    union { unsigned u; float f; } v; v.u = u << 16; return v.f;
}
static __device__ __forceinline__ float bfu_hi(unsigned u) {
    union { unsigned u; float f; } v; v.u = u & 0xFFFF0000u; return v.f;
}

// async global->LDS, 16B/lane; LDS dest = wave-uniform base + lane*16
static __device__ __forceinline__ void gl_lds16(const void* g, void* l) {
    __builtin_amdgcn_global_load_lds(
        (const __attribute__((address_space(1))) unsigned int*)g,
        (__attribute__((address_space(3))) unsigned int*)l, 16, 0, 0);
}

// ---------------------------------------------------------------------------
// K0: prep — key -> khi/klo (bf16 hi + bf16 residual)
// ---------------------------------------------------------------------------
__global__ __launch_bounds__(256) void prep_kernel(const float* __restrict__ key,
                                                   unsigned short* __restrict__ khi,
                                                   unsigned short* __restrict__ klo) {
    size_t gid = (size_t)blockIdx.x * 256 + threadIdx.x;
    size_t base = gid * 8;
    float4 x0 = *(const float4*)(key + base);
    float4 x1 = *(const float4*)(key + base + 4);
    float xs[8] = { x0.x, x0.y, x0.z, x0.w, x1.x, x1.y, x1.z, x1.w };
    unsigned short hi[8], lo[8];
#pragma unroll
    for (int i = 0; i < 8; ++i) {
        hi[i] = f2bf(xs[i]);
        lo[i] = f2bf(xs[i] - bf2f(hi[i]));
    }
    *(bf16x8*)(khi + base) = *(bf16x8*)hi;
    *(bf16x8*)(klo + base) = *(bf16x8*)lo;
}

// ---------------------------------------------------------------------------
// K1: fused q-proj + qk (fp32 exact) + bf16 hi/lo split. 4 rows/block.
// ---------------------------------------------------------------------------
__global__ __launch_bounds__(384) void qk_fused_kernel(const float* __restrict__ query,
                                                       const float* __restrict__ Wq,
                                                       const float* __restrict__ Wk,
                                                       float* __restrict__ qk,
                                                       unsigned short* __restrict__ qkhi,
                                                       unsigned short* __restrict__ qklo) {
    __shared__ float qstage[4][C_];
    __shared__ float qrow[4][C_];
    int ng = blockIdx.x, b = blockIdx.y;
    int t = threadIdx.x;
    int n0 = ng * 4;
#pragma unroll
    for (int i = 0; i < 4; ++i)
        qstage[i][t] = query[((size_t)(b * N_ + n0 + i)) * C_ + t];
    __syncthreads();
    {
        float a[4];
#pragma unroll
        for (int i = 0; i < 4; ++i) a[i] = 0.f;
        const float4* wq = (const float4*)(Wq + (size_t)t * C_);
        for (int c4 = 0; c4 < C_ / 4; ++c4) {
            float4 w = wq[c4];
#pragma unroll
            for (int i = 0; i < 4; ++i)
                a[i] += qstage[i][c4 * 4 + 0] * w.x + qstage[i][c4 * 4 + 1] * w.y
                      + qstage[i][c4 * 4 + 2] * w.z + qstage[i][c4 * 4 + 3] * w.w;
        }
#pragma unroll
        for (int i = 0; i < 4; ++i) qrow[i][t] = a[i] * SCALE_;
    }
    __syncthreads();
    for (int h = 0; h < H_; ++h) {
        float a[4];
#pragma unroll
        for (int i = 0; i < 4; ++i) a[i] = 0.f;
        const float* wk = Wk + (size_t)h * DH_ * C_ + t;
#pragma unroll 4
        for (int d = 0; d < DH_; ++d) {
            float w = wk[(size_t)d * C_];
#pragma unroll
            for (int i = 0; i < 4; ++i) a[i] += qrow[i][h * DH_ + d] * w;
        }
#pragma unroll
        for (int i = 0; i < 4; ++i) {
            size_t o = ((size_t)(b * H_ + h) * N_ + n0 + i) * C_ + t;
            float v = a[i];
            qk[o] = v;
            unsigned short hi = f2bf(v);
            qkhi[o] = hi;
            qklo[o] = f2bf(v - bf2f(hi));
        }
    }
}

// ---------------------------------------------------------------------------
// K2: logits via 3-pass bf16 MFMA + argmax. 64n x 256 tokens,
// XOR-swizzled LDS quarters (conflicts measured 0). UNCHANGED (known-good).
// ---------------------------------------------------------------------------
__global__ __launch_bounds__(256) void attn_kernel(const unsigned short* __restrict__ qkhi,
                                                   const unsigned short* __restrict__ qklo,
                                                   const unsigned short* __restrict__ khi,
                                                   const unsigned short* __restrict__ klo,
                                                   unsigned int* __restrict__ idx,
                                                   unsigned int* __restrict__ flag_cnt,
                                                   unsigned int* __restrict__ flag_list) {
    __shared__ __align__(16) unsigned short sAhi[64 * 32];
    __shared__ __align__(16) unsigned short sAlo[64 * 32];
    __shared__ __align__(16) unsigned short sBhi[256 * 32];
    __shared__ __align__(16) unsigned short sBlo[256 * 32];
    int tid = threadIdx.x;
    int w = tid >> 6, l = tid & 63;
    int wm = w >> 1, wn = w & 1;
    int q4 = l >> 4, lm = l & 15;
    int s0 = blockIdx.x * 256;
    int h = blockIdx.y, b = blockIdx.z;
    size_t kbK = ((size_t)b * S_ + s0) * C_;
    size_t kbA = (size_t)(b * H_ + h) * N_ * C_;
    int trow16 = l >> 2;
    int tquart = ((l & 3) ^ ((l >> 3) & 3)) * 8;
    int sw = (q4 ^ ((lm >> 1) & 3)) * 8;

    f32x4 acc[2][8];
#pragma unroll
    for (int tm = 0; tm < 2; ++tm)
#pragma unroll
        for (int nt = 0; nt < 8; ++nt) acc[tm][nt] = (f32x4)0.f;

    for (int kc = 0; kc < C_; kc += 32) {
        __syncthreads();
#pragma unroll
        for (int i = 0; i < 10; ++i) {
            int gid = w * 10 + i;
            if (gid < 16) {
                gl_lds16(khi + kbK + (size_t)(gid * 16 + trow16) * C_ + kc + tquart,
                         (char*)sBhi + gid * 1024);
            } else if (gid < 32) {
                int g2 = gid - 16;
                gl_lds16(klo + kbK + (size_t)(g2 * 16 + trow16) * C_ + kc + tquart,
                         (char*)sBlo + g2 * 1024);
            } else if (gid < 36) {
                int g2 = gid - 32;
                gl_lds16(qkhi + kbA + (size_t)(g2 * 16 + trow16) * C_ + kc + tquart,
                         (char*)sAhi + g2 * 1024);
            } else {
                int g2 = gid - 36;
                gl_lds16(qklo + kbA + (size_t)(g2 * 16 + trow16) * C_ + kc + tquart,
                         (char*)sAlo + g2 * 1024);
            }
        }
        __syncthreads();
        bf16x8 ah[2], al[2];
#pragma unroll
        for (int tm = 0; tm < 2; ++tm) {
            int ar = (wm * 32 + tm * 16 + lm) * 32 + sw;
            ah[tm] = *(const bf16x8*)&sAhi[ar];
            al[tm] = *(const bf16x8*)&sAlo[ar];
        }
#pragma unroll
        for (int nt = 0; nt < 8; ++nt) {
            int nr = ((wn * 8 + nt) * 16 + lm) * 32 + sw;
            bf16x8 bh = *(const bf16x8*)&sBhi[nr];
            bf16x8 bl = *(const bf16x8*)&sBlo[nr];
#pragma unroll
            for (int tm = 0; tm < 2; ++tm) {
                acc[tm][nt] = __builtin_amdgcn_mfma_f32_16x16x32_bf16(ah[tm], bh, acc[tm][nt], 0, 0, 0);
                acc[tm][nt] = __builtin_amdgcn_mfma_f32_16x16x32_bf16(ah[tm], bl, acc[tm][nt], 0, 0, 0);
                acc[tm][nt] = __builtin_amdgcn_mfma_f32_16x16x32_bf16(al[tm], bh, acc[tm][nt], 0, 0, 0);
            }
        }
    }
    __syncthreads();

    float* rm1 = (float*)sBhi;
    float* rm2 = rm1 + 512;
    int* ri1 = (int*)(rm2 + 512);
    int* ri2 = ri1 + 512;

#pragma unroll
    for (int nt = 0; nt < 8; ++nt) {
        float m1 = -3.4e38f, m2 = -3.4e38f; int i1 = 0, i2 = 0;
#pragma unroll
        for (int tm = 0; tm < 2; ++tm)
#pragma unroll
            for (int r = 0; r < 4; ++r) {
                float v = acc[tm][nt][r];
                int row = wm * 32 + tm * 16 + q4 * 4 + r;
                if (v > m1) { m2 = m1; i2 = i1; m1 = v; i1 = row; }
                else if (v > m2) { m2 = v; i2 = row; }
            }
#pragma unroll
        for (int off = 16; off < 64; off <<= 1) {
            float om1 = __shfl_xor(m1, off), om2 = __shfl_xor(m2, off);
            int oi1 = __shfl_xor(i1, off), oi2 = __shfl_xor(i2, off);
            bool take = (om1 > m1) || (om1 == m1 && oi1 < i1);
            float w1 = take ? om1 : m1; int wi1 = take ? oi1 : i1;
            float l1 = take ? m1 : om1; int li1 = take ? i1 : oi1;
            float s2 = m2; int si2 = i2;
            if (om2 > s2) { s2 = om2; si2 = oi2; }
            if (l1 > s2) { s2 = l1; si2 = li1; }
            m1 = w1; i1 = wi1; m2 = s2; i2 = si2;
        }
        if (q4 == 0) {
            int cw = (wn * 8 + nt) * 16 + lm;
            rm1[wm * 256 + cw] = m1; rm2[wm * 256 + cw] = m2;
            ri1[wm * 256 + cw] = i1; ri2[wm * 256 + cw] = i2;
        }
    }
    __syncthreads();
    float a1 = rm1[tid], a2 = rm2[tid];
    int ai1 = ri1[tid], ai2 = ri2[tid];
    float b1 = rm1[256 + tid], b2 = rm2[256 + tid];
    int bi1 = ri1[256 + tid], bi2 = ri2[256 + tid];
    float w1, s2; int wi1, wi2;
    if (b1 > a1) { w1 = b1; wi1 = bi1; s2 = a1; wi2 = ai1; if (b2 > s2) { s2 = b2; wi2 = bi2; } }
    else         { w1 = a1; wi1 = ai1; s2 = a2; wi2 = ai2; if (b1 > s2) { s2 = b1; wi2 = bi1; } }
    idx[(size_t)(b * H_ + h) * S_ + s0 + tid] = (unsigned)wi1;
    if (w1 - s2 < TAU_) {
        unsigned p = atomicAdd(flag_cnt, 1u);
        if (p < LISTCAP) {
            unsigned tok = (unsigned)((b * H_ + h) * S_ + s0 + tid);
            flag_list[p] = tok | ((unsigned)wi1 << 19) | ((unsigned)wi2 << 25);
        }
    }
}

// ---------------------------------------------------------------------------
// K3: fixup — exact fp32 recompute of two candidate rows for near-ties
// ---------------------------------------------------------------------------
__global__ __launch_bounds__(256) void fixup_kernel(const float* __restrict__ qk,
                                                    const float* __restrict__ key,
                                                    const unsigned int* __restrict__ flag_list,
                                                    const unsigned int* __restrict__ flag_cnt,
                                                    unsigned int* __restrict__ idx) {
    int w = threadIdx.x >> 6, l = threadIdx.x & 63;
    unsigned total = flag_cnt[0];
    if (total > LISTCAP) total = LISTCAP;
    for (unsigned t = blockIdx.x * 4 + w; t < total; t += gridDim.x * 4) {
        unsigned e = flag_list[t];
        unsigned tok = e & 0x7FFFFu;
        int i1 = (int)((e >> 19) & 63u), i2 = (int)((e >> 25) & 63u);
        unsigned bh = tok >> 12;
        unsigned s = tok & 4095u;
        unsigned bb = bh / H_;
        int l32 = l & 31;
        const float* qrow = qk + ((size_t)bh * N_ + (l < 32 ? i1 : i2)) * C_ + l32 * 12;
        const float* krow = key + ((size_t)bb * S_ + s) * C_ + l32 * 12;
        float sum = 0.f;
#pragma unroll
        for (int c = 0; c < 12; ++c) sum += qrow[c] * krow[c];
#pragma unroll
        for (int off = 1; off < 32; off <<= 1) sum += __shfl_xor(sum, off);
        float d1 = __shfl(sum, 0);
        float d2 = __shfl(sum, 32);
        int win = (d2 > d1 || (d2 == d1 && i2 < i1)) ? i2 : i1;
        if (l == 0) idx[(size_t)bh * S_ + s] = (unsigned)win;
    }
}

// ---------------------------------------------------------------------------
// K4: hist_build — per (b,h): histogram -> scan -> counting-sort placement
// ---------------------------------------------------------------------------
__global__ __launch_bounds__(256) void hist_build_kernel(const unsigned int* __restrict__ idx,
                                                         unsigned int* __restrict__ offs,
                                                         unsigned int* __restrict__ order) {
    __shared__ unsigned int cnts[N_];
    __shared__ unsigned int pos[N_];
    int tid = threadIdx.x;
    int bh = blockIdx.x;
    if (tid < N_) cnts[tid] = 0u;
    __syncthreads();
    const unsigned int* idxp = idx + (size_t)bh * S_;
    for (int s = tid; s < S_; s += 256) atomicAdd(&cnts[idxp[s]], 1u);
    __syncthreads();
    if (tid < N_) {
        unsigned v = cnts[tid];
        unsigned x = v;
#pragma unroll
        for (int off = 1; off < 64; off <<= 1) {
            unsigned y = __shfl_up(x, off);
            if (tid >= off) x += y;
        }
        unsigned excl = x - v;
        pos[tid] = excl;
        offs[(size_t)bh * 65 + tid] = excl;
        if (tid == 63) offs[(size_t)bh * 65 + 64] = x;   // == S_
    }
    __syncthreads();
    unsigned int* op = order + (size_t)bh * S_;
    for (int s = tid; s < S_; s += 256) {
        unsigned g = idxp[s];
        unsigned p = atomicAdd(&pos[g], 1u);
        op[p] = (unsigned)s;
    }
}

// ---------------------------------------------------------------------------
// K5: agg2 — per (group, half): contiguous token list -> register accumulation
// ---------------------------------------------------------------------------
__global__ __launch_bounds__(256) void agg2_kernel(const unsigned short* __restrict__ khi,
                                                   const unsigned int* __restrict__ order,
                                                   const unsigned int* __restrict__ offs,
                                                   float* __restrict__ gpart) {
    int tid = threadIdx.x;
    int w = tid >> 6, l = tid & 63;
    int h = blockIdx.y, b = blockIdx.z;
    int bh = b * H_ + h;
    int wid = blockIdx.x * 4 + w;       // 0..127
    int g = wid >> 1, part = wid & 1;
    unsigned beg = offs[(size_t)bh * 65 + g];
    unsigned end = offs[(size_t)bh * 65 + g + 1];
    int cnt = (int)(end - beg);
    float inv = 1.f / ((float)cnt + 1.f);
    const unsigned int* op = order + (size_t)bh * S_ + beg;
    const unsigned int* kbase = (const unsigned int*)(khi + (size_t)b * S_ * C_);
    float a0 = 0.f, a1 = 0.f, a2 = 0.f, a3 = 0.f, a4 = 0.f, a5 = 0.f;
    for (int base = part * 64; base < cnt; base += 128) {
        int m = cnt - base; if (m > 64) m = 64;
        unsigned sv = (l < m) ? op[base + l] : 0u;
        for (int i = 0; i < m; ++i) {
            int s = (int)__shfl((int)sv, i);
            const unsigned int* kp = kbase + (size_t)s * (C_ / 2) + l * 3;
            unsigned u0 = kp[0], u1 = kp[1], u2 = kp[2];
            a0 += bfu_lo(u0); a1 += bfu_hi(u0);
            a2 += bfu_lo(u1); a3 += bfu_hi(u1);
            a4 += bfu_lo(u2); a5 += bfu_hi(u2);
        }
    }
    float* gp = gpart + (((size_t)bh * 2 + part) * N_ + g) * C_ + l * 6;
    float2 o0 = { a0 * inv, a1 * inv };
    float2 o1 = { a2 * inv, a3 * inv };
    float2 o2 = { a4 * inv, a5 * inv };
    ((float2*)gp)[0] = o0; ((float2*)gp)[1] = o1; ((float2*)gp)[2] = o2;
}

// ---------------------------------------------------------------------------
// K6: gv — ONE WAVE PER (bh, group): 6144 independent waves (24/CU), no
// serialized group loop (round-6 had 96 blocks x 16 barrier-separated iters
// = 4.4% occupancy, 182 us). Lane d: dot(row, Wv[h*64+d]); LDS row reads are
// same-address broadcast (free); Wv is L2-resident.
// ---------------------------------------------------------------------------
__global__ __launch_bounds__(256) void gv_kernel(const float* __restrict__ gpart,
                                                 const float* __restrict__ Wv,
                                                 float* __restrict__ gvn) {
    __shared__ float rows[4][C_];
    int tid = threadIdx.x;
    int w = tid >> 6, l = tid & 63;
    int h = blockIdx.y, b = blockIdx.z;
    int bh = b * H_ + h;
    int g = blockIdx.x * 4 + w;
    const float* s0 = gpart + (((size_t)bh * 2 + 0) * N_ + g) * C_;
    const float* s1 = gpart + (((size_t)bh * 2 + 1) * N_ + g) * C_;
    for (int i = l; i < C_ / 4; i += 64) {
        float4 x = ((const float4*)s0)[i];
        float4 y = ((const float4*)s1)[i];
        float4 z = { x.x + y.x, x.y + y.y, x.z + y.z, x.w + y.w };
        *(float4*)&rows[w][i * 4] = z;
    }
    __syncthreads();   // one barrier; waves independent afterwards
    const float* wrow = Wv + (size_t)(h * DH_ + l) * C_;
    float acc = 0.f;
#pragma unroll 8
    for (int c4 = 0; c4 < C_ / 4; ++c4) {
        float4 a = *(const float4*)&rows[w][c4 * 4];
        float4 wv = *(const float4*)&wrow[c4 * 4];
        acc += a.x * wv.x + a.y * wv.y + a.z * wv.z + a.w * wv.w;
    }
    gvn[((size_t)bh * N_ + g) * DH_ + l] = acc;
}

// ---------------------------------------------------------------------------
// K7: out[b,n,j] = sum_{h,d} gvn[b,h,n,d] * Wp[j, h*64+d] + bp[j]
// ---------------------------------------------------------------------------
__global__ __launch_bounds__(384) void out_kernel(const float* __restrict__ gvn,
                                                  const float* __restrict__ Wp,
                                                  const float* __restrict__ bp,
                                                  float* __restrict__ out) {
    __shared__ float vals[C_];
    int bn = blockIdx.x;
    int b = bn >> 6, n = bn & 63;
    int t = threadIdx.x;
    int h = t >> 6, d = t & 63;
    vals[t] = gvn[((size_t)(b * H_ + h) * N_ + n) * DH_ + d];
    __syncthreads();
    const float4* w4 = (const float4*)(Wp + (size_t)t * C_);
    const float4* v4 = (const float4*)vals;
    float s = bp[t];
#pragma unroll 8
    for (int i = 0; i < C_ / 4; ++i) {
        float4 a = v4[i]; float4 w = w4[i];
        s += a.x * w.x + a.y * w.y + a.z * w.z + a.w * w.w;
    }
    out[(size_t)bn * C_ + t] = s;
}

// ---------------------------------------------------------------------------
extern "C" void kernel_launch(void* const* d_in, const int* in_sizes, int n_in,
                              void* d_out, int out_size, void* d_ws, size_t ws_size,
                              hipStream_t stream) {
    (void)in_sizes; (void)n_in; (void)out_size; (void)ws_size;
    const float* query = (const float*)d_in[0];
    const float* key   = (const float*)d_in[1];
    const float* Wq    = (const float*)d_in[2];
    const float* Wk    = (const float*)d_in[3];
    const float* Wv    = (const float*)d_in[4];
    const float* Wp    = (const float*)d_in[5];
    const float* bp    = (const float*)d_in[6];
    float* out = (float*)d_out;

    char* ws = (char*)d_ws;
    size_t off = 0;
    unsigned short* khi  = (unsigned short*)(ws + off); off += (size_t)B_ * S_ * C_ * 2;
    unsigned short* klo  = (unsigned short*)(ws + off); off += (size_t)B_ * S_ * C_ * 2;
    float* qk            = (float*)(ws + off);          off += (size_t)B_ * H_ * N_ * C_ * 4;
    unsigned short* qkhi = (unsigned short*)(ws + off); off += (size_t)B_ * H_ * N_ * C_ * 2;
    unsigned short* qklo = (unsigned short*)(ws + off); off += (size_t)B_ * H_ * N_ * C_ * 2;
    unsigned int* idx    = (unsigned int*)(ws + off);   off += (size_t)B_ * H_ * S_ * 4;
    unsigned int* order  = (unsigned int*)(ws + off);   off += (size_t)B_ * H_ * S_ * 4;
    unsigned int* offs   = (unsigned int*)(ws + off);   off += (size_t)B_ * H_ * 65 * 4;
    float* gpart         = (float*)(ws + off);          off += (size_t)B_ * H_ * 2 * N_ * C_ * 4;
    float* gvn           = (float*)(ws + off);          off += (size_t)B_ * H_ * N_ * DH_ * 4;
    unsigned int* fcnt   = (unsigned int*)(ws + off);   off += 256;
    unsigned int* flist  = (unsigned int*)(ws + off);   off += (size_t)LISTCAP * 4;

    hipMemsetAsync(fcnt, 0, 256, stream);

    prep_kernel<<<(B_ * S_ * C_ / 8) / 256, 256, 0, stream>>>(key, khi, klo);
    qk_fused_kernel<<<dim3(N_ / 4, B_), 384, 0, stream>>>(query, Wq, Wk, qk, qkhi, qklo);
    attn_kernel<<<dim3(S_ / 256, H_, B_), 256, 0, stream>>>(qkhi, qklo, khi, klo, idx, fcnt, flist);
    fixup_kernel<<<256, 256, 0, stream>>>(qk, key, flist, fcnt, idx);
    hist_build_kernel<<<B_ * H_, 256, 0, stream>>>(idx, offs, order);
    agg2_kernel<<<dim3(32, H_, B_), 256, 0, stream>>>(khi, order, offs, gpart);
    gv_kernel<<<dim3(16, H_, B_), 256, 0, stream>>>(gpart, Wv, gvn);
    out_kernel<<<B_ * N_, 384, 0, stream>>>(gvn, Wp, bp, out);
}